// Round 3
// baseline (168471.777 us; speedup 1.0000x reference)
//
#include <hip/hip_runtime.h>

#define D_ 512
#define H_ 1024
#define L_ 4096
#define CS_ 64
#define NCH_ 64
#define RACT_ 256
#define LR_ 0.1f
#define MOM_ 0.95f
#define NSA_ 3.4445f
#define NSB_ (-4.7750f)
#define NSC_ 2.0315f

#define NB_ 256   // blocks (1 per CU)
#define TPB_ 512  // threads per block (8 waves)
#define NTH_ (NB_ * TPB_)

using bf16x8 = __attribute__((ext_vector_type(8))) short;
using f32x4  = __attribute__((ext_vector_type(4))) float;

__device__ __forceinline__ short f2bs(float f) {
  unsigned u = __builtin_bit_cast(unsigned, f);
  unsigned r = (u + 0x7fffu + ((u >> 16) & 1u)) >> 16;  // RNE
  return (short)r;
}
__device__ __forceinline__ float bs2f(short s) {
  unsigned u = ((unsigned)(unsigned short)s) << 16;
  return __builtin_bit_cast(float, u);
}
__device__ __forceinline__ void split2(float v, short& h, short& l) {
  h = f2bs(v);
  l = f2bs(v - bs2f(h));
}

#define MFMA16(a, b, c) __builtin_amdgcn_mfma_f32_16x16x32_bf16(a, b, c, 0, 0, 0)

__device__ __forceinline__ void zero_acc(f32x4 (&acc)[2][2]) {
  f32x4 z = {0.f, 0.f, 0.f, 0.f};
  acc[0][0] = z; acc[0][1] = z; acc[1][0] = z; acc[1][1] = z;
}

// Split-bf16 NT GEMM 32x32 wave tile: C[m][n] = sum_k A[m][k]*Bt[n][k].
// 3 MFMA passes (hh, hl, lh); lo*lo dropped.
__device__ __forceinline__ void mma_nt_split(
    const short* __restrict__ Ah, const short* __restrict__ Al, int lda,
    const short* __restrict__ Bh, const short* __restrict__ Bl, int ldb,
    int K, int m0, int n0, f32x4 (&acc)[2][2]) {
  const int lane = threadIdx.x & 63;
  const int lm = lane & 15, kq = lane >> 4;
  const size_t aoff = (size_t)(m0 + lm) * lda + kq * 8;
  const size_t boff = (size_t)(n0 + lm) * ldb + kq * 8;
  const size_t a1 = aoff + (size_t)16 * lda;
  const size_t b1 = boff + (size_t)16 * ldb;
#pragma unroll 4
  for (int k = 0; k < K; k += 32) {
    bf16x8 ah0 = *(const bf16x8*)(Ah + aoff + k);
    bf16x8 ah1 = *(const bf16x8*)(Ah + a1 + k);
    bf16x8 bh0 = *(const bf16x8*)(Bh + boff + k);
    bf16x8 bh1 = *(const bf16x8*)(Bh + b1 + k);
    bf16x8 al0 = *(const bf16x8*)(Al + aoff + k);
    bf16x8 al1 = *(const bf16x8*)(Al + a1 + k);
    bf16x8 bl0 = *(const bf16x8*)(Bl + boff + k);
    bf16x8 bl1 = *(const bf16x8*)(Bl + b1 + k);
    acc[0][0] = MFMA16(ah0, bh0, acc[0][0]);
    acc[0][1] = MFMA16(ah0, bh1, acc[0][1]);
    acc[1][0] = MFMA16(ah1, bh0, acc[1][0]);
    acc[1][1] = MFMA16(ah1, bh1, acc[1][1]);
    acc[0][0] = MFMA16(ah0, bl0, acc[0][0]);
    acc[0][1] = MFMA16(ah0, bl1, acc[0][1]);
    acc[1][0] = MFMA16(ah1, bl0, acc[1][0]);
    acc[1][1] = MFMA16(ah1, bl1, acc[1][1]);
    acc[0][0] = MFMA16(al0, bh0, acc[0][0]);
    acc[0][1] = MFMA16(al0, bh1, acc[0][1]);
    acc[1][0] = MFMA16(al1, bh0, acc[1][0]);
    acc[1][1] = MFMA16(al1, bh1, acc[1][1]);
  }
}

#define EPI_FOR                                               \
  _Pragma("unroll") for (int i = 0; i < 2; i++)               \
  _Pragma("unroll") for (int j = 0; j < 2; j++)               \
  _Pragma("unroll") for (int e = 0; e < 4; e++)

#define EPI_IDX int gm = m0 + i * 16 + kq * 4 + e, gn = n0 + j * 16 + lm;

struct P {
  const float *kin, *vin, *w1in, *w2in;
  float *w1f, *w2f, *buf1, *buf2t, *Gn1, *Gn2, *deriv, *partial;
  short *w1bth, *w1btl, *w2bh, *w2bl, *w2bth, *w2btl;
  short *Xph0, *Xpl0, *Xth0, *Xtl0, *Xph1, *Xpl1, *Xth1, *Xtl1;
  short *Ah, *Al, *Bmh, *Bml;
  short *l1h, *l1l, *l1Th, *l1Tl, *dOh, *dOl, *dOTh, *dOTl, *dpTh, *dpTl;
  short *xah, *xal, *xaTh, *xaTl;
  short *xfh, *xfl, *l1fh, *l1fl;
  float *out;
  unsigned *bar;  // [0]=cnt, [1]=gen
};

// device-scope grid barrier (co-resident via cooperative launch)
__device__ __forceinline__ void gsync(unsigned* bar, unsigned& gen) {
  __threadfence();
  __syncthreads();
  if (threadIdx.x == 0) {
    unsigned g = gen + 1;
    unsigned a = __hip_atomic_fetch_add(&bar[0], 1u, __ATOMIC_ACQ_REL,
                                        __HIP_MEMORY_SCOPE_AGENT);
    if (a == NB_ - 1) {
      __hip_atomic_store(&bar[0], 0u, __ATOMIC_RELAXED, __HIP_MEMORY_SCOPE_AGENT);
      __hip_atomic_store(&bar[1], g, __ATOMIC_RELEASE, __HIP_MEMORY_SCOPE_AGENT);
    } else {
      while (__hip_atomic_load(&bar[1], __ATOMIC_ACQUIRE,
                               __HIP_MEMORY_SCOPE_AGENT) < g) {
        __builtin_amdgcn_s_sleep(4);
      }
    }
  }
  __syncthreads();
  __threadfence();
  gen = gen + 1;
}

__global__ void muon_barinit(unsigned* bar) { bar[0] = 0u; bar[1] = 0u; }

__global__ __launch_bounds__(TPB_, 2) void muon_mega(P p) {
  const int bid = blockIdx.x;
  const int tid = threadIdx.x;
  const int w = tid >> 6;
  const int lane = tid & 63;
  const int lm = lane & 15, kq = lane >> 4;
  const size_t MSZ = (size_t)D_ * H_;
  const size_t ASZ = (size_t)D_ * D_;
  unsigned gen = 0;
  __shared__ float sred[12];

  // ---- stage: init (weights, split mirrors, zero momentum) ----
  for (int idx = bid * TPB_ + tid; idx < (int)MSZ; idx += NTH_) {
    float a = p.w1in[idx], b = p.w2in[idx];
    p.w1f[idx] = a; p.w2f[idx] = b;
    p.buf1[idx] = 0.f; p.buf2t[idx] = 0.f;
    short h, l;
    int d1 = idx >> 10, h1 = idx & 1023;        // w1 [d][h]
    split2(a, h, l);
    p.w1bth[(size_t)h1 * D_ + d1] = h; p.w1btl[(size_t)h1 * D_ + d1] = l;
    int h2 = idx >> 9, d2 = idx & 511;          // w2 [h][d]
    split2(b, h, l);
    p.w2bh[idx] = h; p.w2bl[idx] = l;
    p.w2bth[(size_t)d2 * H_ + h2] = h; p.w2btl[(size_t)d2 * H_ + h2] = l;
  }
  gsync(p.bar, gen);

  short* Xph[2] = {p.Xph0, p.Xph1};
  short* Xpl[2] = {p.Xpl0, p.Xpl1};
  short* Xth[2] = {p.Xth0, p.Xth1};
  short* Xtl[2] = {p.Xtl0, p.Xtl1};

  for (int c = 0; c < NCH_ - 1; c++) {
    // ---- stage kx: gather + split active rows (256 x 512), 1 elem/thread --
    {
      int idx = bid * TPB_ + tid;                // NTH_ == RACT_*D_ exactly
      int r = idx >> 9, d = idx & 511;
      int b = r >> 4, t = r & 15;
      float v = p.kin[(size_t)(b * L_ + c * CS_ + t) * D_ + d];
      short h, l; split2(v, h, l);
      p.xah[idx] = h; p.xal[idx] = l;
      p.xaTh[(size_t)d * RACT_ + r] = h; p.xaTl[(size_t)d * RACT_ + r] = l;
    }
    gsync(p.bar, gen);

    // ---- stage k1a: l1 = tanh(x @ w1); 256 tiles, K=512 ----
    for (int t = bid + NB_ * w; t < 256; t += NB_ * 8) {
      int m0 = (t >> 5) * 32, n0 = (t & 31) * 32;
      f32x4 acc[2][2]; zero_acc(acc);
      mma_nt_split(p.xah, p.xal, D_, p.w1bth, p.w1btl, D_, D_, m0, n0, acc);
      EPI_FOR {
        EPI_IDX
        float l1v = tanhf(acc[i][j][e]);
        short h, l; split2(l1v, h, l);
        p.l1h[(size_t)gm * H_ + gn] = h; p.l1l[(size_t)gm * H_ + gn] = l;
        p.l1Th[(size_t)gn * RACT_ + gm] = h; p.l1Tl[(size_t)gn * RACT_ + gm] = l;
        p.deriv[(size_t)gm * H_ + gn] = 1.f - l1v * l1v;
      }
    }
    gsync(p.bar, gen);

    // ---- stage k1b: dOut = mask*2/1024*(l1@w2 - vt); 128 tiles, K=1024 ----
    for (int t = bid + NB_ * w; t < 128; t += NB_ * 8) {
      int m0 = (t >> 4) * 32, n0 = (t & 15) * 32;
      f32x4 acc[2][2]; zero_acc(acc);
      mma_nt_split(p.l1h, p.l1l, H_, p.w2bth, p.w2btl, H_, H_, m0, n0, acc);
      EPI_FOR {
        EPI_IDX
        int b = gm >> 4, tt = gm & 15;
        bool mk = (tt <= b) && (b - tt <= 7);
        float dv = 0.f;
        if (mk) {
          float vt = p.vin[(size_t)(b * L_ + c * CS_ + tt) * D_ + gn];
          dv = (2.0f / 1024.0f) * (acc[i][j][e] - vt);
        }
        short h, l; split2(dv, h, l);
        p.dOh[(size_t)gm * D_ + gn] = h; p.dOl[(size_t)gm * D_ + gn] = l;
        p.dOTh[(size_t)gn * RACT_ + gm] = h; p.dOTl[(size_t)gn * RACT_ + gm] = l;
      }
    }
    gsync(p.bar, gen);

    // ---- stage k1c: dpre = (dOut @ w2^T) * deriv; 256 tiles, K=512 ----
    for (int t = bid + NB_ * w; t < 256; t += NB_ * 8) {
      int m0 = (t >> 5) * 32, n0 = (t & 31) * 32;
      f32x4 acc[2][2]; zero_acc(acc);
      mma_nt_split(p.dOh, p.dOl, D_, p.w2bh, p.w2bl, D_, D_, m0, n0, acc);
      EPI_FOR {
        EPI_IDX
        float dp = acc[i][j][e] * p.deriv[(size_t)gm * H_ + gn];
        short h, l; split2(dp, h, l);
        p.dpTh[(size_t)gn * RACT_ + gm] = h; p.dpTl[(size_t)gn * RACT_ + gm] = l;
      }
    }
    gsync(p.bar, gen);

    // ---- stage k2: grads + momentum + nesterov; 1024 tiles, K=256 ----
    for (int t = bid + NB_ * w; t < 1024; t += NB_ * 8) {
      int job = t >> 9, tt = t & 511;
      int m0 = (tt >> 5) * 32, n0 = (tt & 31) * 32;
      const short* Ah = job ? p.dOTh : p.xaTh;
      const short* Al = job ? p.dOTl : p.xaTl;
      const short* Bh = job ? p.l1Th : p.dpTh;
      const short* Bl = job ? p.l1Tl : p.dpTl;
      float* buf = job ? p.buf2t : p.buf1;
      float* Gn  = job ? p.Gn2 : p.Gn1;
      f32x4 acc[2][2]; zero_acc(acc);
      mma_nt_split(Ah, Al, RACT_, Bh, Bl, RACT_, RACT_, m0, n0, acc);
      float part = 0.f;
      EPI_FOR {
        EPI_IDX
        size_t idx = (size_t)gm * H_ + gn;
        float g = acc[i][j][e];
        float bn = MOM_ * buf[idx] + g;
        buf[idx] = bn;
        float gv = g + MOM_ * bn;  // nesterov
        Gn[idx] = gv;
        part += gv * gv;
      }
      for (int off = 32; off > 0; off >>= 1) part += __shfl_down(part, off, 64);
      if (lane == 0) p.partial[t] = part;
    }
    gsync(p.bar, gen);

    // ---- stage k3: redundant deterministic norm reduce + normalize ----
    {
#pragma unroll
      for (int job = 0; job < 2; job++) {
        float v = p.partial[job * 512 + tid];   // TPB_ == 512
        for (int off = 32; off > 0; off >>= 1) v += __shfl_down(v, off, 64);
        if (lane == 0) sred[w] = v;
        __syncthreads();
        if (tid == 0) {
          float tsum = 0.f;
#pragma unroll
          for (int kk = 0; kk < 8; kk++) tsum += sred[kk];
          sred[8 + job] = tsum;
        }
        __syncthreads();
      }
      float sc[2];
      sc[0] = 1.f / (sqrtf(sred[8]) + 1e-7f);
      sc[1] = 1.f / (sqrtf(sred[9]) + 1e-7f);
#pragma unroll
      for (int job = 0; job < 2; job++) {
        const float* G = job ? p.Gn2 : p.Gn1;
        short* xph = Xph[0] + job * MSZ;
        short* xpl = Xpl[0] + job * MSZ;
        short* xth = Xth[0] + job * MSZ;
        short* xtl = Xtl[0] + job * MSZ;
        for (int idx = bid * TPB_ + tid; idx < (int)MSZ; idx += NTH_) {
          int m = idx >> 10, n = idx & 1023;
          short h, l; split2(G[idx] * sc[job], h, l);
          xph[idx] = h; xpl[idx] = l;
          xth[(size_t)n * D_ + m] = h; xtl[(size_t)n * D_ + m] = l;
        }
      }
    }
    gsync(p.bar, gen);

    // ---- NS iterations ----
    for (int it = 0; it < 5; it++) {
      int cur = it & 1, nx = cur ^ 1;
      int last = (it == 4);
      // k4: A = X @ X^T; 512 tiles, K=1024
      for (int t = bid + NB_ * w; t < 512; t += NB_ * 8) {
        int job = t >> 8, tt = t & 255;
        int m0 = (tt >> 4) * 32, n0 = (tt & 15) * 32;
        const short* xh = Xph[cur] + job * MSZ;
        const short* xl = Xpl[cur] + job * MSZ;
        f32x4 acc[2][2]; zero_acc(acc);
        mma_nt_split(xh, xl, H_, xh, xl, H_, H_, m0, n0, acc);
        short* ah = p.Ah + job * ASZ;
        short* al = p.Al + job * ASZ;
        EPI_FOR {
          EPI_IDX
          short h, l; split2(acc[i][j][e], h, l);
          ah[(size_t)gm * D_ + gn] = h; al[(size_t)gm * D_ + gn] = l;
        }
      }
      gsync(p.bar, gen);
      // k5: Bm = b*A + c*(A@A); 512 tiles, K=512
      for (int t = bid + NB_ * w; t < 512; t += NB_ * 8) {
        int job = t >> 8, tt = t & 255;
        int m0 = (tt >> 4) * 32, n0 = (tt & 15) * 32;
        const short* ah = p.Ah + job * ASZ;
        const short* al = p.Al + job * ASZ;
        f32x4 acc[2][2]; zero_acc(acc);
        mma_nt_split(ah, al, D_, ah, al, D_, D_, m0, n0, acc);  // A symmetric
        short* bh = p.Bmh + job * ASZ;
        short* bl = p.Bml + job * ASZ;
        EPI_FOR {
          EPI_IDX
          size_t ii = (size_t)gm * D_ + gn;
          float av = bs2f(ah[ii]) + bs2f(al[ii]);
          short h, l; split2(NSB_ * av + NSC_ * acc[i][j][e], h, l);
          bh[ii] = h; bl[ii] = l;
        }
      }
      gsync(p.bar, gen);
      // k6: Xn = a*X + Bm@X (last: weight update); 1024 tiles, K=512
      for (int t = bid + NB_ * w; t < 1024; t += NB_ * 8) {
        int job = t >> 9, tt = t & 511;
        int m0 = (tt >> 5) * 32, n0 = (tt & 31) * 32;
        const short* bmh = p.Bmh + job * ASZ;
        const short* bml = p.Bml + job * ASZ;
        f32x4 acc[2][2]; zero_acc(acc);
        mma_nt_split(bmh, bml, D_, Xth[cur] + job * MSZ, Xtl[cur] + job * MSZ,
                     D_, D_, m0, n0, acc);
        EPI_FOR {
          EPI_IDX
          size_t idx = (size_t)gm * H_ + gn;
          float xv = NSA_ * (bs2f(Xph[cur][job * MSZ + idx]) +
                             bs2f(Xpl[cur][job * MSZ + idx])) + acc[i][j][e];
          short h, l;
          if (!last) {
            split2(xv, h, l);
            Xph[nx][job * MSZ + idx] = h; Xpl[nx][job * MSZ + idx] = l;
            Xth[nx][job * MSZ + (size_t)gn * D_ + gm] = h;
            Xtl[nx][job * MSZ + (size_t)gn * D_ + gm] = l;
          } else if (job == 0) {
            float nv = p.w1f[idx] - LR_ * xv;   // w1 [d][h] == X1 orientation
            p.w1f[idx] = nv;
            split2(nv, h, l);
            p.w1bth[(size_t)gn * D_ + gm] = h; p.w1btl[(size_t)gn * D_ + gm] = l;
          } else {
            size_t i2 = (size_t)gn * D_ + gm;   // w2 [h][d], u2 = X2^T
            float nv = p.w2f[i2] - LR_ * xv;
            p.w2f[i2] = nv;
            split2(nv, h, l);
            p.w2bh[i2] = h; p.w2bl[i2] = l;
            p.w2bth[idx] = h; p.w2btl[idx] = l;
          }
        }
      }
      gsync(p.bar, gen);
    }
  }

  // ---- stage kxf: split full last chunk (1024 x 512) ----
  for (int idx = bid * TPB_ + tid; idx < (int)MSZ; idx += NTH_) {
    int r = idx >> 9, d = idx & 511;
    int b = r >> 6, t = r & 63;
    float v = p.kin[(size_t)(b * L_ + (NCH_ - 1) * CS_ + t) * D_ + d];
    short h, l; split2(v, h, l);
    p.xfh[idx] = h; p.xfl[idx] = l;
  }
  gsync(p.bar, gen);

  // ---- stage k8a: final forward layer 1; 1024 tiles, K=512 ----
  for (int t = bid + NB_ * w; t < 1024; t += NB_ * 8) {
    int m0 = (t >> 5) * 32, n0 = (t & 31) * 32;
    f32x4 acc[2][2]; zero_acc(acc);
    mma_nt_split(p.xfh, p.xfl, D_, p.w1bth, p.w1btl, D_, D_, m0, n0, acc);
    EPI_FOR {
      EPI_IDX
      short h, l; split2(tanhf(acc[i][j][e]), h, l);
      p.l1fh[(size_t)gm * H_ + gn] = h; p.l1fl[(size_t)gm * H_ + gn] = l;
    }
  }
  gsync(p.bar, gen);

  // ---- stage k8b: final forward layer 2 -> out; 512 tiles, K=1024 ----
  for (int t = bid + NB_ * w; t < 512; t += NB_ * 8) {
    int m0 = (t >> 4) * 32, n0 = (t & 15) * 32;
    f32x4 acc[2][2]; zero_acc(acc);
    mma_nt_split(p.l1fh, p.l1fl, H_, p.w2bth, p.w2btl, H_, H_, m0, n0, acc);
    EPI_FOR {
      EPI_IDX
      p.out[(size_t)gm * D_ + gn] = acc[i][j][e];
    }
  }
}

extern "C" void kernel_launch(void* const* d_in, const int* in_sizes, int n_in,
                              void* d_out, int out_size, void* d_ws, size_t ws_size,
                              hipStream_t stream) {
  char* pp = (char*)d_ws;
  auto take = [&](size_t bytes) {
    char* r = pp; pp += (bytes + 255) & ~(size_t)255; return r;
  };
  const size_t MSZ = (size_t)D_ * H_;
  const size_t ASZ = (size_t)D_ * D_;
  const size_t L1SZ = (size_t)RACT_ * H_;
  const size_t DOSZ = (size_t)RACT_ * D_;

  P p;
  p.kin  = (const float*)d_in[0];
  p.vin  = (const float*)d_in[1];
  p.w1in = (const float*)d_in[2];
  p.w2in = (const float*)d_in[3];
  p.out  = (float*)d_out;

  p.w1f   = (float*)take(MSZ * 4);
  p.w2f   = (float*)take(MSZ * 4);
  p.buf1  = (float*)take(MSZ * 4);
  p.buf2t = (float*)take(MSZ * 4);
  p.Gn1   = (float*)take(MSZ * 4);
  p.Gn2   = (float*)take(MSZ * 4);
  p.deriv = (float*)take(L1SZ * 4);
  p.partial = (float*)take(1024 * 4);
  p.w1bth = (short*)take(MSZ * 2);
  p.w1btl = (short*)take(MSZ * 2);
  p.w2bh  = (short*)take(MSZ * 2);
  p.w2bl  = (short*)take(MSZ * 2);
  p.w2bth = (short*)take(MSZ * 2);
  p.w2btl = (short*)take(MSZ * 2);
  p.Xph0 = (short*)take(2 * MSZ * 2);
  p.Xpl0 = (short*)take(2 * MSZ * 2);
  p.Xth0 = (short*)take(2 * MSZ * 2);
  p.Xtl0 = (short*)take(2 * MSZ * 2);
  p.Xph1 = (short*)take(2 * MSZ * 2);
  p.Xpl1 = (short*)take(2 * MSZ * 2);
  p.Xth1 = (short*)take(2 * MSZ * 2);
  p.Xtl1 = (short*)take(2 * MSZ * 2);
  p.Ah  = (short*)take(2 * ASZ * 2);
  p.Al  = (short*)take(2 * ASZ * 2);
  p.Bmh = (short*)take(2 * ASZ * 2);
  p.Bml = (short*)take(2 * ASZ * 2);
  p.l1h  = (short*)take(L1SZ * 2);
  p.l1l  = (short*)take(L1SZ * 2);
  p.l1Th = (short*)take(L1SZ * 2);
  p.l1Tl = (short*)take(L1SZ * 2);
  p.dOh  = (short*)take(DOSZ * 2);
  p.dOl  = (short*)take(DOSZ * 2);
  p.dOTh = (short*)take(DOSZ * 2);
  p.dOTl = (short*)take(DOSZ * 2);
  p.dpTh = (short*)take(L1SZ * 2);
  p.dpTl = (short*)take(L1SZ * 2);
  p.xah  = (short*)take(DOSZ * 2);
  p.xal  = (short*)take(DOSZ * 2);
  p.xaTh = (short*)take(DOSZ * 2);
  p.xaTl = (short*)take(DOSZ * 2);
  p.bar  = (unsigned*)take(256);
  // final-stage buffers alias dead NS buffers:
  p.xfh  = p.Xph0;            // 1024x512
  p.xfl  = p.Xph0 + MSZ;
  p.l1fh = p.Xpl0;            // 1024x1024 = 2*MSZ
  p.l1fl = p.Xph1;

  muon_barinit<<<1, 1, 0, stream>>>(p.bar);
  void* kp[] = { &p };
  hipLaunchCooperativeKernel(muon_mega, dim3(NB_), dim3(TPB_), kp, 0, stream);
}

// Round 5
// 17951.401 us; speedup vs baseline: 9.3849x; 9.3849x over previous
//
#include <hip/hip_runtime.h>

#define D_ 512
#define H_ 1024
#define L_ 4096
#define CS_ 64
#define NCH_ 64
#define RACT_ 256
#define LR_ 0.1f
#define MOM_ 0.95f
#define NSA_ 3.4445f
#define NSB_ (-4.7750f)
#define NSC_ 2.0315f

using bf16x8 = __attribute__((ext_vector_type(8))) short;
using f32x4  = __attribute__((ext_vector_type(4))) float;
using s16x4  = __attribute__((ext_vector_type(4))) short;

__device__ __forceinline__ short f2bs(float f) {
  unsigned u = __builtin_bit_cast(unsigned, f);
  unsigned r = (u + 0x7fffu + ((u >> 16) & 1u)) >> 16;  // RNE
  return (short)r;
}
__device__ __forceinline__ float bs2f(short s) {
  unsigned u = ((unsigned)(unsigned short)s) << 16;
  return __builtin_bit_cast(float, u);
}
__device__ __forceinline__ void split2(float v, short& h, short& l) {
  h = f2bs(v);
  l = f2bs(v - bs2f(h));
}

#define MFMA16(a, b, c) __builtin_amdgcn_mfma_f32_16x16x32_bf16(a, b, c, 0, 0, 0)

// Split-bf16 NT GEMM, one 32x32 output tile per block, 4 waves split K 4 ways.
// Each wave: 2x2 16x16x32 fragments over K/4; partials to LDS; deterministic
// 4-way fp32 sum. Returns 4 consecutive outputs per thread at (row, c0..c0+3).
template <int K>
__device__ __forceinline__ f32x4 gemm_ks(
    const short* __restrict__ Ah, const short* __restrict__ Al, int lda,
    const short* __restrict__ Bh, const short* __restrict__ Bl, int ldb,
    int m0, int n0, float (*lds)[32][32], int& row, int& c0) {
  const int tid = threadIdx.x;
  const int w = tid >> 6, lane = tid & 63;
  const int lm = lane & 15, kq = lane >> 4;
  constexpr int KQ = K >> 2;  // per-wave K range
  f32x4 z = {0.f, 0.f, 0.f, 0.f};
  f32x4 acc[2][2] = {{z, z}, {z, z}};
  const size_t ao = (size_t)(m0 + lm) * lda + w * KQ + kq * 8;
  const size_t bo = (size_t)(n0 + lm) * ldb + w * KQ + kq * 8;
  const size_t ao1 = ao + (size_t)16 * lda;
  const size_t bo1 = bo + (size_t)16 * ldb;
#pragma unroll 4
  for (int k = 0; k < KQ; k += 32) {
    bf16x8 ah0 = *(const bf16x8*)(Ah + ao + k);
    bf16x8 ah1 = *(const bf16x8*)(Ah + ao1 + k);
    bf16x8 bh0 = *(const bf16x8*)(Bh + bo + k);
    bf16x8 bh1 = *(const bf16x8*)(Bh + bo1 + k);
    bf16x8 al0 = *(const bf16x8*)(Al + ao + k);
    bf16x8 al1 = *(const bf16x8*)(Al + ao1 + k);
    bf16x8 bl0 = *(const bf16x8*)(Bl + bo + k);
    bf16x8 bl1 = *(const bf16x8*)(Bl + bo1 + k);
    acc[0][0] = MFMA16(ah0, bh0, acc[0][0]);
    acc[0][1] = MFMA16(ah0, bh1, acc[0][1]);
    acc[1][0] = MFMA16(ah1, bh0, acc[1][0]);
    acc[1][1] = MFMA16(ah1, bh1, acc[1][1]);
    acc[0][0] = MFMA16(ah0, bl0, acc[0][0]);
    acc[0][1] = MFMA16(ah0, bl1, acc[0][1]);
    acc[1][0] = MFMA16(ah1, bl0, acc[1][0]);
    acc[1][1] = MFMA16(ah1, bl1, acc[1][1]);
    acc[0][0] = MFMA16(al0, bh0, acc[0][0]);
    acc[0][1] = MFMA16(al0, bh1, acc[0][1]);
    acc[1][0] = MFMA16(al1, bh0, acc[1][0]);
    acc[1][1] = MFMA16(al1, bh1, acc[1][1]);
  }
#pragma unroll
  for (int i = 0; i < 2; i++)
#pragma unroll
    for (int j = 0; j < 2; j++)
#pragma unroll
      for (int e = 0; e < 4; e++)
        lds[w][i * 16 + kq * 4 + e][j * 16 + lm] = acc[i][j][e];
  __syncthreads();
  row = tid >> 3;
  c0 = (tid & 7) * 4;
  f32x4 s = *(const f32x4*)&lds[0][row][c0];
  s += *(const f32x4*)&lds[1][row][c0];
  s += *(const f32x4*)&lds[2][row][c0];
  s += *(const f32x4*)&lds[3][row][c0];
  return s;
}

#define GEMM_SHARED __shared__ float lds[4][32][32];

// ---------------- init: fp32 weights, split mirrors, zero momentum ----------
__global__ __launch_bounds__(256) void muon_init(
    const float* __restrict__ w1in, const float* __restrict__ w2in,
    float* __restrict__ w1f, float* __restrict__ w2f,
    float* __restrict__ buf1, float* __restrict__ buf2t,
    short* __restrict__ w1bth, short* __restrict__ w1btl,
    short* __restrict__ w2bh, short* __restrict__ w2bl,
    short* __restrict__ w2bth, short* __restrict__ w2btl) {
  int idx = blockIdx.x * 256 + threadIdx.x;  // D_*H_ threads
  float a = w1in[idx], b = w2in[idx];
  w1f[idx] = a; w2f[idx] = b;
  buf1[idx] = 0.f; buf2t[idx] = 0.f;
  short h, l;
  int d1 = idx >> 10, h1 = idx & 1023;        // w1 [d][h]
  split2(a, h, l);
  w1bth[(size_t)h1 * D_ + d1] = h; w1btl[(size_t)h1 * D_ + d1] = l;
  int h2 = idx >> 9, d2 = idx & 511;          // w2 [h][d]
  split2(b, h, l);
  w2bh[idx] = h; w2bl[idx] = l;
  w2bth[(size_t)d2 * H_ + h2] = h; w2btl[(size_t)d2 * H_ + h2] = l;
}

// ---------------- kx: split active x chunk (256 rows) + transpose -----------
__global__ __launch_bounds__(256) void muon_kx(
    const float* __restrict__ kin, int c,
    short* __restrict__ xah, short* __restrict__ xal,
    short* __restrict__ xaTh, short* __restrict__ xaTl) {
  int base = blockIdx.x * 1024 + threadIdx.x;  // 128 blocks * 4 elems
#pragma unroll
  for (int r4 = 0; r4 < 4; r4++) {
    int idx = base + r4 * 256;
    int r = idx >> 9, d = idx & 511;
    int b = r >> 4, t = r & 15;
    float v = kin[(size_t)(b * L_ + c * CS_ + t) * D_ + d];
    short h, l; split2(v, h, l);
    xah[idx] = h; xal[idx] = l;
    xaTh[(size_t)d * RACT_ + r] = h; xaTl[(size_t)d * RACT_ + r] = l;
  }
}

// ---------------- k1a: l1 = tanh(x @ w1); grid 256 --------------------------
__global__ __launch_bounds__(256, 4) void muon_k1a(
    const short* __restrict__ xah, const short* __restrict__ xal,
    const short* __restrict__ w1bth, const short* __restrict__ w1btl,
    short* __restrict__ l1h, short* __restrict__ l1l,
    short* __restrict__ l1Th, short* __restrict__ l1Tl,
    float* __restrict__ deriv) {
  GEMM_SHARED
  const int m0 = (blockIdx.x >> 5) * 32, n0 = (blockIdx.x & 31) * 32;
  int row, c0;
  f32x4 s = gemm_ks<D_>(xah, xal, D_, w1bth, w1btl, D_, m0, n0, lds, row, c0);
  int gm = m0 + row, gn0 = n0 + c0;
  s16x4 hv, lv; f32x4 dv;
#pragma unroll
  for (int cc = 0; cc < 4; cc++) {
    float l1v = tanhf(s[cc]);
    short h, l; split2(l1v, h, l);
    hv[cc] = h; lv[cc] = l; dv[cc] = 1.f - l1v * l1v;
    l1Th[(size_t)(gn0 + cc) * RACT_ + gm] = h;
    l1Tl[(size_t)(gn0 + cc) * RACT_ + gm] = l;
  }
  *(s16x4*)&l1h[(size_t)gm * H_ + gn0] = hv;
  *(s16x4*)&l1l[(size_t)gm * H_ + gn0] = lv;
  *(f32x4*)&deriv[(size_t)gm * H_ + gn0] = dv;
}

// ---------------- k1b: dOut = mask*2/1024*(l1@w2 - vt); grid 128 ------------
__global__ __launch_bounds__(256, 4) void muon_k1b(
    const float* __restrict__ vin,
    const short* __restrict__ l1h, const short* __restrict__ l1l,
    const short* __restrict__ w2bth, const short* __restrict__ w2btl,
    short* __restrict__ dOh, short* __restrict__ dOl,
    short* __restrict__ dOTh, short* __restrict__ dOTl, int c) {
  GEMM_SHARED
  const int m0 = (blockIdx.x >> 4) * 32, n0 = (blockIdx.x & 15) * 32;
  int row, c0;
  f32x4 s = gemm_ks<H_>(l1h, l1l, H_, w2bth, w2btl, H_, m0, n0, lds, row, c0);
  int gm = m0 + row, gn0 = n0 + c0;
  int b = gm >> 4, t = gm & 15;
  bool mk = (t <= b) && (b - t <= 7);
  f32x4 vt4 = {0.f, 0.f, 0.f, 0.f};
  if (mk) vt4 = *(const f32x4*)&vin[(size_t)(b * L_ + c * CS_ + t) * D_ + gn0];
  s16x4 hv, lv;
#pragma unroll
  for (int cc = 0; cc < 4; cc++) {
    float dv = mk ? (2.0f / 1024.0f) * (s[cc] - vt4[cc]) : 0.f;
    short h, l; split2(dv, h, l);
    hv[cc] = h; lv[cc] = l;
    dOTh[(size_t)(gn0 + cc) * RACT_ + gm] = h;
    dOTl[(size_t)(gn0 + cc) * RACT_ + gm] = l;
  }
  *(s16x4*)&dOh[(size_t)gm * D_ + gn0] = hv;
  *(s16x4*)&dOl[(size_t)gm * D_ + gn0] = lv;
}

// ---------------- k1c: dpre = (dOut @ w2^T) * deriv; grid 256 ---------------
__global__ __launch_bounds__(256, 4) void muon_k1c(
    const short* __restrict__ dOh, const short* __restrict__ dOl,
    const short* __restrict__ w2bh, const short* __restrict__ w2bl,
    const float* __restrict__ deriv,
    short* __restrict__ dpTh, short* __restrict__ dpTl) {
  GEMM_SHARED
  const int m0 = (blockIdx.x >> 5) * 32, n0 = (blockIdx.x & 31) * 32;
  int row, c0;
  f32x4 s = gemm_ks<D_>(dOh, dOl, D_, w2bh, w2bl, D_, m0, n0, lds, row, c0);
  int gm = m0 + row, gn0 = n0 + c0;
  f32x4 dv = *(const f32x4*)&deriv[(size_t)gm * H_ + gn0];
#pragma unroll
  for (int cc = 0; cc < 4; cc++) {
    float dp = s[cc] * dv[cc];
    short h, l; split2(dp, h, l);
    dpTh[(size_t)(gn0 + cc) * RACT_ + gm] = h;
    dpTl[(size_t)(gn0 + cc) * RACT_ + gm] = l;
  }
}

// ---------------- k2: grads + momentum + nesterov; grid 1024 ----------------
__global__ __launch_bounds__(256, 4) void muon_k2(
    const short* __restrict__ xaTh, const short* __restrict__ xaTl,
    const short* __restrict__ dpTh, const short* __restrict__ dpTl,
    const short* __restrict__ dOTh, const short* __restrict__ dOTl,
    const short* __restrict__ l1Th, const short* __restrict__ l1Tl,
    float* __restrict__ buf1, float* __restrict__ buf2t,
    float* __restrict__ Gn1, float* __restrict__ Gn2,
    float* __restrict__ partial) {
  GEMM_SHARED
  __shared__ float sred[4];
  const int bid = blockIdx.x;
  const int job = bid >> 9, tt = bid & 511;
  const int m0 = (tt >> 5) * 32, n0 = (tt & 31) * 32;
  const short* Ah = job ? dOTh : xaTh;
  const short* Al = job ? dOTl : xaTl;
  const short* Bh = job ? l1Th : dpTh;
  const short* Bl = job ? l1Tl : dpTl;
  float* buf = job ? buf2t : buf1;
  float* Gn  = job ? Gn2 : Gn1;
  int row, c0;
  f32x4 s = gemm_ks<RACT_>(Ah, Al, RACT_, Bh, Bl, RACT_, m0, n0, lds, row, c0);
  int gm = m0 + row, gn0 = n0 + c0;
  size_t idx0 = (size_t)gm * H_ + gn0;
  f32x4 bv = *(const f32x4*)&buf[idx0];
  f32x4 gv;
  float part = 0.f;
#pragma unroll
  for (int cc = 0; cc < 4; cc++) {
    float bn = MOM_ * bv[cc] + s[cc];
    bv[cc] = bn;
    float g = s[cc] + MOM_ * bn;  // nesterov
    gv[cc] = g;
    part += g * g;
  }
  *(f32x4*)&buf[idx0] = bv;
  *(f32x4*)&Gn[idx0] = gv;
  for (int off = 32; off > 0; off >>= 1) part += __shfl_down(part, off, 64);
  if ((threadIdx.x & 63) == 0) sred[threadIdx.x >> 6] = part;
  __syncthreads();
  if (threadIdx.x == 0) partial[bid] = sred[0] + sred[1] + sred[2] + sred[3];
}

// ---------------- k3: deterministic norm + normalize; grid 512 --------------
__global__ __launch_bounds__(256) void muon_k3(
    const float* __restrict__ Gn1, const float* __restrict__ Gn2,
    const float* __restrict__ partial,
    short* __restrict__ Xph, short* __restrict__ Xpl,
    short* __restrict__ Xth, short* __restrict__ Xtl) {
  const int job = blockIdx.x >> 8;       // 2 jobs x 256 blocks
  const int blk = blockIdx.x & 255;
  const int t = threadIdx.x;
  const int w = t >> 6;
  __shared__ float sred[6];
  float sc[2];
#pragma unroll
  for (int jb = 0; jb < 2; jb++) {
    float v = partial[jb * 512 + t] + partial[jb * 512 + 256 + t];
    for (int off = 32; off > 0; off >>= 1) v += __shfl_down(v, off, 64);
    if ((t & 63) == 0) sred[w] = v;
    __syncthreads();
    if (t == 0) sred[4 + jb] = sred[0] + sred[1] + sred[2] + sred[3];
    __syncthreads();
  }
  sc[0] = 1.f / (sqrtf(sred[4]) + 1e-7f);
  sc[1] = 1.f / (sqrtf(sred[5]) + 1e-7f);
  const size_t MSZ = (size_t)D_ * H_;
  const float* G = job ? Gn2 : Gn1;
  short* xph = Xph + (size_t)job * MSZ;
  short* xpl = Xpl + (size_t)job * MSZ;
  short* xth = Xth + (size_t)job * MSZ;
  short* xtl = Xtl + (size_t)job * MSZ;
  float scl = sc[job];
  int base = blk * 2048 + t;
#pragma unroll
  for (int r = 0; r < 8; r++) {
    int idx = base + r * 256;
    int m = idx >> 10, n = idx & 1023;
    short h, l; split2(G[idx] * scl, h, l);
    xph[idx] = h; xpl[idx] = l;
    xth[(size_t)n * D_ + m] = h; xtl[(size_t)n * D_ + m] = l;
  }
}

// ---------------- k4: A = X @ X^T; grid 512 ---------------------------------
__global__ __launch_bounds__(256, 4) void muon_k4(
    const short* __restrict__ Xph, const short* __restrict__ Xpl,
    short* __restrict__ Ah, short* __restrict__ Al) {
  GEMM_SHARED
  const int bid = blockIdx.x;
  const int job = bid >> 8, tt = bid & 255;
  const int m0 = (tt >> 4) * 32, n0 = (tt & 15) * 32;
  const size_t MSZ = (size_t)D_ * H_;
  const short* xh = Xph + (size_t)job * MSZ;
  const short* xl = Xpl + (size_t)job * MSZ;
  int row, c0;
  f32x4 s = gemm_ks<H_>(xh, xl, H_, xh, xl, H_, m0, n0, lds, row, c0);
  int gm = m0 + row, gn0 = n0 + c0;
  short* ah = Ah + (size_t)job * (D_ * D_);
  short* al = Al + (size_t)job * (D_ * D_);
  s16x4 hv, lv;
#pragma unroll
  for (int cc = 0; cc < 4; cc++) {
    short h, l; split2(s[cc], h, l);
    hv[cc] = h; lv[cc] = l;
  }
  *(s16x4*)&ah[(size_t)gm * D_ + gn0] = hv;
  *(s16x4*)&al[(size_t)gm * D_ + gn0] = lv;
}

// ---------------- k5: Bm = b*A + c*(A@A); grid 512 --------------------------
__global__ __launch_bounds__(256, 4) void muon_k5(
    const short* __restrict__ Ah, const short* __restrict__ Al,
    short* __restrict__ Bmh, short* __restrict__ Bml) {
  GEMM_SHARED
  const int bid = blockIdx.x;
  const int job = bid >> 8, tt = bid & 255;
  const int m0 = (tt >> 4) * 32, n0 = (tt & 15) * 32;
  const short* ah = Ah + (size_t)job * (D_ * D_);
  const short* al = Al + (size_t)job * (D_ * D_);
  int row, c0;
  f32x4 s = gemm_ks<D_>(ah, al, D_, ah, al, D_, m0, n0, lds, row, c0);  // A sym
  int gm = m0 + row, gn0 = n0 + c0;
  s16x4 ahv = *(const s16x4*)&ah[(size_t)gm * D_ + gn0];
  s16x4 alv = *(const s16x4*)&al[(size_t)gm * D_ + gn0];
  short* bh = Bmh + (size_t)job * (D_ * D_);
  short* bl = Bml + (size_t)job * (D_ * D_);
  s16x4 hv, lv;
#pragma unroll
  for (int cc = 0; cc < 4; cc++) {
    float av = bs2f(ahv[cc]) + bs2f(alv[cc]);
    short h, l; split2(NSB_ * av + NSC_ * s[cc], h, l);
    hv[cc] = h; lv[cc] = l;
  }
  *(s16x4*)&bh[(size_t)gm * D_ + gn0] = hv;
  *(s16x4*)&bl[(size_t)gm * D_ + gn0] = lv;
}

// ---------------- k6: Xn = a*X + Bm@X (last: weight update); grid 1024 ------
__global__ __launch_bounds__(256, 4) void muon_k6(
    const short* __restrict__ Bmh, const short* __restrict__ Bml,
    const short* __restrict__ Xth, const short* __restrict__ Xtl,
    const short* __restrict__ Xph, const short* __restrict__ Xpl,
    short* __restrict__ XphN, short* __restrict__ XplN,
    short* __restrict__ XthN, short* __restrict__ XtlN,
    float* __restrict__ w1f, float* __restrict__ w2f,
    short* __restrict__ w1bth, short* __restrict__ w1btl,
    short* __restrict__ w2bh, short* __restrict__ w2bl,
    short* __restrict__ w2bth, short* __restrict__ w2btl, int last) {
  GEMM_SHARED
  const size_t MSZ = (size_t)D_ * H_;
  const int bid = blockIdx.x;
  const int job = bid >> 9, tt = bid & 511;
  const int m0 = (tt >> 5) * 32, n0 = (tt & 31) * 32;
  const short* bmh = Bmh + (size_t)job * (D_ * D_);
  const short* bml = Bml + (size_t)job * (D_ * D_);
  int row, c0;
  f32x4 s = gemm_ks<D_>(bmh, bml, D_, Xth + job * MSZ, Xtl + job * MSZ, D_,
                        m0, n0, lds, row, c0);
  int gm = m0 + row, gn0 = n0 + c0;
  size_t idx0 = (size_t)gm * H_ + gn0;
  s16x4 ph = *(const s16x4*)&Xph[job * MSZ + idx0];
  s16x4 pl = *(const s16x4*)&Xpl[job * MSZ + idx0];
  f32x4 xv;
#pragma unroll
  for (int cc = 0; cc < 4; cc++)
    xv[cc] = NSA_ * (bs2f(ph[cc]) + bs2f(pl[cc])) + s[cc];
  if (!last) {
    s16x4 hv, lv;
#pragma unroll
    for (int cc = 0; cc < 4; cc++) {
      short h, l; split2(xv[cc], h, l);
      hv[cc] = h; lv[cc] = l;
      XthN[job * MSZ + (size_t)(gn0 + cc) * D_ + gm] = h;
      XtlN[job * MSZ + (size_t)(gn0 + cc) * D_ + gm] = l;
    }
    *(s16x4*)&XphN[job * MSZ + idx0] = hv;
    *(s16x4*)&XplN[job * MSZ + idx0] = lv;
  } else if (job == 0) {
    f32x4 wv = *(const f32x4*)&w1f[idx0];
#pragma unroll
    for (int cc = 0; cc < 4; cc++) {
      float nv = wv[cc] - LR_ * xv[cc];   // w1 [d][h] == X1 orientation
      wv[cc] = nv;
      short h, l; split2(nv, h, l);
      w1bth[(size_t)(gn0 + cc) * D_ + gm] = h;
      w1btl[(size_t)(gn0 + cc) * D_ + gm] = l;
    }
    *(f32x4*)&w1f[idx0] = wv;
  } else {
    s16x4 hv, lv;
#pragma unroll
    for (int cc = 0; cc < 4; cc++) {
      size_t i2 = (size_t)(gn0 + cc) * D_ + gm;  // w2 [h][d], u2 = X2^T
      float nv = w2f[i2] - LR_ * xv[cc];
      w2f[i2] = nv;
      short h, l; split2(nv, h, l);
      w2bh[i2] = h; w2bl[i2] = l;
      hv[cc] = h; lv[cc] = l;
    }
    *(s16x4*)&w2bth[idx0] = hv;
    *(s16x4*)&w2btl[idx0] = lv;
  }
}

// ---------------- kxf: split full last chunk (1024 x 512) -------------------
__global__ __launch_bounds__(256) void muon_kxf(
    const float* __restrict__ kin, short* __restrict__ xfh, short* __restrict__ xfl) {
  int base = blockIdx.x * 1024 + threadIdx.x;  // 512 blocks * 4 elems
#pragma unroll
  for (int r4 = 0; r4 < 4; r4++) {
    int idx = base + r4 * 256;
    int r = idx >> 9, d = idx & 511;
    int b = r >> 6, t = r & 63;
    float v = kin[(size_t)(b * L_ + (NCH_ - 1) * CS_ + t) * D_ + d];
    short h, l; split2(v, h, l);
    xfh[idx] = h; xfl[idx] = l;
  }
}

// ---------------- k8a: final forward layer 1; grid 1024 ---------------------
__global__ __launch_bounds__(256, 4) void muon_k8a(
    const short* __restrict__ xfh, const short* __restrict__ xfl,
    const short* __restrict__ w1bth, const short* __restrict__ w1btl,
    short* __restrict__ l1fh, short* __restrict__ l1fl) {
  GEMM_SHARED
  const int m0 = (blockIdx.x >> 5) * 32, n0 = (blockIdx.x & 31) * 32;
  int row, c0;
  f32x4 s = gemm_ks<D_>(xfh, xfl, D_, w1bth, w1btl, D_, m0, n0, lds, row, c0);
  int gm = m0 + row, gn0 = n0 + c0;
  s16x4 hv, lv;
#pragma unroll
  for (int cc = 0; cc < 4; cc++) {
    short h, l; split2(tanhf(s[cc]), h, l);
    hv[cc] = h; lv[cc] = l;
  }
  *(s16x4*)&l1fh[(size_t)gm * H_ + gn0] = hv;
  *(s16x4*)&l1fl[(size_t)gm * H_ + gn0] = lv;
}

// ---------------- k8b: final forward layer 2 -> out; grid 512 ---------------
__global__ __launch_bounds__(256, 4) void muon_k8b(
    const short* __restrict__ l1fh, const short* __restrict__ l1fl,
    const short* __restrict__ w2bth, const short* __restrict__ w2btl,
    float* __restrict__ out) {
  GEMM_SHARED
  const int m0 = (blockIdx.x >> 4) * 32, n0 = (blockIdx.x & 15) * 32;
  int row, c0;
  f32x4 s = gemm_ks<H_>(l1fh, l1fl, H_, w2bth, w2btl, H_, m0, n0, lds, row, c0);
  int gm = m0 + row, gn0 = n0 + c0;
  *(f32x4*)&out[(size_t)gm * D_ + gn0] = s;
}

extern "C" void kernel_launch(void* const* d_in, const int* in_sizes, int n_in,
                              void* d_out, int out_size, void* d_ws, size_t ws_size,
                              hipStream_t stream) {
  const float* kin  = (const float*)d_in[0];
  const float* vin  = (const float*)d_in[1];
  const float* w1in = (const float*)d_in[2];
  const float* w2in = (const float*)d_in[3];
  float* out = (float*)d_out;

  char* pp = (char*)d_ws;
  auto take = [&](size_t bytes) {
    char* r = pp; pp += (bytes + 255) & ~(size_t)255; return r;
  };
  const size_t MSZ = (size_t)D_ * H_;
  const size_t ASZ = (size_t)D_ * D_;
  const size_t L1SZ = (size_t)RACT_ * H_;
  const size_t DOSZ = (size_t)RACT_ * D_;

  float* w1f   = (float*)take(MSZ * 4);
  float* w2f   = (float*)take(MSZ * 4);
  float* buf1  = (float*)take(MSZ * 4);
  float* buf2t = (float*)take(MSZ * 4);
  float* Gn1   = (float*)take(MSZ * 4);
  float* Gn2   = (float*)take(MSZ * 4);
  float* deriv = (float*)take(L1SZ * 4);
  float* partial = (float*)take(1024 * 4);
  short* w1bth = (short*)take(MSZ * 2);
  short* w1btl = (short*)take(MSZ * 2);
  short* w2bh  = (short*)take(MSZ * 2);
  short* w2bl  = (short*)take(MSZ * 2);
  short* w2bth = (short*)take(MSZ * 2);
  short* w2btl = (short*)take(MSZ * 2);
  short* Xph[2], *Xpl[2], *Xth[2], *Xtl[2];
  for (int i = 0; i < 2; i++) {
    Xph[i] = (short*)take(2 * MSZ * 2);
    Xpl[i] = (short*)take(2 * MSZ * 2);
    Xth[i] = (short*)take(2 * MSZ * 2);
    Xtl[i] = (short*)take(2 * MSZ * 2);
  }
  short* Ah  = (short*)take(2 * ASZ * 2);
  short* Al  = (short*)take(2 * ASZ * 2);
  short* Bmh = (short*)take(2 * ASZ * 2);
  short* Bml = (short*)take(2 * ASZ * 2);
  short* l1h  = (short*)take(L1SZ * 2);
  short* l1l  = (short*)take(L1SZ * 2);
  short* l1Th = (short*)take(L1SZ * 2);
  short* l1Tl = (short*)take(L1SZ * 2);
  short* dOh  = (short*)take(DOSZ * 2);
  short* dOl  = (short*)take(DOSZ * 2);
  short* dOTh = (short*)take(DOSZ * 2);
  short* dOTl = (short*)take(DOSZ * 2);
  short* dpTh = (short*)take(L1SZ * 2);
  short* dpTl = (short*)take(L1SZ * 2);
  short* xah  = (short*)take(DOSZ * 2);
  short* xal  = (short*)take(DOSZ * 2);
  short* xaTh = (short*)take(DOSZ * 2);
  short* xaTl = (short*)take(DOSZ * 2);
  // final-stage buffers alias dead NS buffers:
  short* xfh  = Xph[0];             // 1024x512
  short* xfl  = Xph[0] + MSZ;
  short* l1fh = Xpl[0];             // 1024x1024 = 2*MSZ
  short* l1fl = Xph[1];

  muon_init<<<2048, 256, 0, stream>>>(w1in, w2in, w1f, w2f, buf1, buf2t,
                                      w1bth, w1btl, w2bh, w2bl, w2bth, w2btl);
  for (int c = 0; c < NCH_ - 1; c++) {
    muon_kx<<<128, 256, 0, stream>>>(kin, c, xah, xal, xaTh, xaTl);
    muon_k1a<<<256, 256, 0, stream>>>(xah, xal, w1bth, w1btl,
                                      l1h, l1l, l1Th, l1Tl, deriv);
    muon_k1b<<<128, 256, 0, stream>>>(vin, l1h, l1l, w2bth, w2btl,
                                      dOh, dOl, dOTh, dOTl, c);
    muon_k1c<<<256, 256, 0, stream>>>(dOh, dOl, w2bh, w2bl, deriv, dpTh, dpTl);
    muon_k2<<<1024, 256, 0, stream>>>(xaTh, xaTl, dpTh, dpTl, dOTh, dOTl,
                                      l1Th, l1Tl, buf1, buf2t, Gn1, Gn2, partial);
    muon_k3<<<512, 256, 0, stream>>>(Gn1, Gn2, partial,
                                     Xph[0], Xpl[0], Xth[0], Xtl[0]);
    for (int it = 0; it < 5; it++) {
      int cur = it & 1, nx = cur ^ 1;
      muon_k4<<<512, 256, 0, stream>>>(Xph[cur], Xpl[cur], Ah, Al);
      muon_k5<<<512, 256, 0, stream>>>(Ah, Al, Bmh, Bml);
      muon_k6<<<1024, 256, 0, stream>>>(Bmh, Bml, Xth[cur], Xtl[cur],
                                        Xph[cur], Xpl[cur],
                                        Xph[nx], Xpl[nx], Xth[nx], Xtl[nx],
                                        w1f, w2f, w1bth, w1btl, w2bh, w2bl,
                                        w2bth, w2btl, it == 4 ? 1 : 0);
    }
  }
  muon_kxf<<<512, 256, 0, stream>>>(kin, xfh, xfl);
  muon_k8a<<<1024, 256, 0, stream>>>(xfh, xfl, w1bth, w1btl, l1fh, l1fl);
  muon_k8b<<<512, 256, 0, stream>>>(l1fh, l1fl, w2bth, w2btl, out);
}